// Round 21
// baseline (831.246 us; speedup 1.0000x reference)
//
#include <hip/hip_runtime.h>
#include <hip/hip_bf16.h>
#include <cstdint>

typedef __attribute__((ext_vector_type(8))) short u16x8;
typedef _Float16 f16_t;
typedef __attribute__((ext_vector_type(8))) f16_t f16x8;
typedef __attribute__((ext_vector_type(4))) float f32x4;

#define L_TOT 4608
#define L_TXT 512
#define L_IMG 4096
#define NH 24
#define HD 128
#define DMODEL 3072
#define NQKV 9216
#define LOG2E 1.44269504088896340736f
#define S_SHIFT 32.0f

__device__ __forceinline__ ushort f2h(float f) {
  union { f16_t h; ushort u; } c; c.h = (f16_t)f; return c.u;
}
__device__ __forceinline__ float h2f(ushort u) {
  union { ushort u; f16_t h; } c; c.u = u; return (float)c.h;
}
__device__ __forceinline__ ushort f2bf(float f) {
  union { float f; uint32_t i; } c; c.f = f;
  uint32_t i = c.i;
  return (ushort)((i + 0x7FFFu + ((i >> 16) & 1u)) >> 16);
}
__device__ __forceinline__ float bf2f(ushort u) {
  union { uint32_t i; float f; } c; c.i = ((uint32_t)u) << 16; return c.f;
}
__device__ __forceinline__ void gload16(const ushort* g, ushort* l) {
  __builtin_amdgcn_global_load_lds((const __attribute__((address_space(1))) void*)g,
                                   (__attribute__((address_space(3))) void*)l, 16, 0, 0);
}

// ------- cvt_f32_f16: elementwise f32 -> fp16, 8 elems/thread ---------------------------
__global__ void cvt_f32_f16(const float* __restrict__ src, ushort* __restrict__ dst,
                            int n8) {
  const int i = blockIdx.x * 256 + threadIdx.x;
  if (i >= n8) return;
  const f32x4 a = *(const f32x4*)(src + (size_t)i * 8);
  const f32x4 b = *(const f32x4*)(src + (size_t)i * 8 + 4);
  alignas(16) ushort o[8];
#pragma unroll
  for (int j = 0; j < 4; ++j) { o[j] = f2h(a[j]); o[4 + j] = f2h(b[j]); }
  *(u16x8*)(dst + (size_t)i * 8) = *(const u16x8*)o;
}

// ------- tconv_w: f32 weight [3072][C], col-slice c0..c0+Nsl -> fp16 [Nsl][3072] --------
__global__ void tconv_w(const float* __restrict__ src, int C, int c0,
                        ushort* __restrict__ dst) {
  __shared__ ushort tile[64][72];
  const int nb = blockIdx.x << 6, kb = blockIdx.y << 6;
  const int t = threadIdx.x;
  const int lr = t >> 2, lc = (t & 3) << 4;
  const float* sp = src + (size_t)(kb + lr) * C + c0 + nb + lc;
  const f32x4 v0 = *(const f32x4*)sp;
  const f32x4 v1 = *(const f32x4*)(sp + 4);
  const f32x4 v2 = *(const f32x4*)(sp + 8);
  const f32x4 v3 = *(const f32x4*)(sp + 12);
#pragma unroll
  for (int i = 0; i < 4; ++i) {
    tile[lr][lc + i]      = f2h(v0[i]);
    tile[lr][lc + 4 + i]  = f2h(v1[i]);
    tile[lr][lc + 8 + i]  = f2h(v2[i]);
    tile[lr][lc + 12 + i] = f2h(v3[i]);
  }
  __syncthreads();
  const int cl = t & 63, rb = (t >> 6) << 4;
  alignas(16) ushort o[16];
#pragma unroll
  for (int i = 0; i < 16; ++i) o[i] = tile[rb + i][cl];
  ushort* dp = dst + (size_t)(nb + cl) * DMODEL + kb + rb;
  *(u16x8*)dp       = *(const u16x8*)o;
  *(u16x8*)(dp + 8) = *(const u16x8*)(o + 8);
}

// ------- rowsum: per-row f32 sum of bf16 P[4608][4608] ---------------------------------
__global__ void rowsum(const ushort* __restrict__ P, float* __restrict__ RS) {
  const int r = blockIdx.x, tid = threadIdx.x;
  const ushort* Pr = P + (size_t)r * L_TOT;
  float s = 0.f;
#pragma unroll
  for (int j = 0; j < 18; ++j) s += bf2f(Pr[tid + (j << 8)]);
#pragma unroll
  for (int o = 1; o < 64; o <<= 1) s += __shfl_xor(s, o);
  __shared__ float reds[4];
  const int wave = tid >> 6, lane = tid & 63;
  if (lane == 0) reds[wave] = s;
  __syncthreads();
  if (tid == 0) RS[r] = reds[0] + reds[1] + reds[2] + reds[3];
}

// =========== gemm256: 256x256, BK=64, 8 waves, 2-phase counted schedule ================
// Body identical to round-18/20 best. Per-block operand select for merged enc+img
// dispatches (m0 < 512 -> BtLo/biasLo). MODE 2 uses bf16 MFMA (P, V^T are bf16).
// Epilogues: MODE 0 qkv scatter (Q,K fp16 rows; V -> bf16, transposed through LDS
// directly into V^T[d][l], replacing the tconv_h kernel); MODE 1 f32 out + bias
// (merged proj, row remap); MODE 2 fp16 out scaled by 1/RS[row] (biasLo = rowsum,
// fused softmax normalization); MODE 3 bf16 exp2((acc-32)*log2e) (fused softmax exp).
template <int MODE>
__global__ __launch_bounds__(512, 2) void gemm256(
    const ushort* __restrict__ A, int lda,
    const ushort* __restrict__ BtLo, const ushort* __restrict__ BtHi, int ldb,
    int N, int K, void* __restrict__ out0, ushort* __restrict__ out1,
    ushort* __restrict__ out2, const float* __restrict__ biasLo,
    const float* __restrict__ biasHi, int n_base) {
  __shared__ __align__(16) ushort lds[2][2][2][8192];  // [buf][khalf][mat][256*32]
  int lin = blockIdx.y * gridDim.x + blockIdx.x;
  {
    const int nwg = gridDim.x * gridDim.y;
    const int q8 = nwg >> 3, r8 = nwg & 7;
    const int xcd = lin & 7, idx = lin >> 3;
    lin = (xcd < r8 ? xcd * (q8 + 1) : r8 * (q8 + 1) + (xcd - r8) * q8) + idx;
  }
  const int m0 = (lin % gridDim.x) << 8, n0 = (lin / gridDim.x) << 8;
  const ushort* Bt = (m0 < L_TXT) ? BtLo : BtHi;
  const int tid = threadIdx.x, w = tid >> 6, lane = tid & 63;
  const int wm = w >> 2, wn = w & 3;
  const int lr = lane & 15, g4 = lane >> 4;
  const int srow = lane >> 2;
  const int soff = 8 * ((lane & 3) ^ ((lane >> 3) & 3));  // k-elems within half
  f32x4 acc[8][4];
#pragma unroll
  for (int a = 0; a < 8; ++a)
#pragma unroll
    for (int b = 0; b < 4; ++b) acc[a][b] = (f32x4){0.f, 0.f, 0.f, 0.f};
  const int nt = K >> 6;

  auto stageA = [&](int h, int kt, int b) {
#pragma unroll
    for (int i = 0; i < 2; ++i) {
      const int j = w * 2 + i;
      gload16(A + (size_t)(m0 + 16 * j + srow) * lda + (kt << 6) + 32 * h + soff,
              &lds[b][h][0][j * 512]);
    }
  };
  auto stageB = [&](int h, int kt, int b) {
#pragma unroll
    for (int i = 0; i < 2; ++i) {
      const int j = w * 2 + i;
      gload16(Bt + (size_t)(n0 + 16 * j + srow) * ldb + (kt << 6) + 32 * h + soff,
              &lds[b][h][1][j * 512]);
    }
  };
  auto readA = [&](int h, int mi, int b) -> u16x8 {
    const int row = wm * 128 + mi * 16 + lr;
    const int byte = row * 64 + ((g4 ^ ((row >> 1) & 3)) << 4);
    return *(const u16x8*)((const char*)&lds[b][h][0][0] + byte);
  };
  auto readB = [&](int h, int ni, int b) -> u16x8 {
    const int row = wn * 64 + ni * 16 + lr;
    const int byte = row * 64 + ((g4 ^ ((row >> 1) & 3)) << 4);
    return *(const u16x8*)((const char*)&lds[b][h][1][0] + byte);
  };
  auto MFMA = [&](u16x8 a, u16x8 b, f32x4 c) -> f32x4 {
    if constexpr (MODE == 2)
      return __builtin_amdgcn_mfma_f32_16x16x32_bf16(a, b, c, 0, 0, 0);
    else
      return __builtin_amdgcn_mfma_f32_16x16x32_f16(
          __builtin_bit_cast(f16x8, a), __builtin_bit_cast(f16x8, b), c, 0, 0, 0);
  };

  // prologue: stage tile 0 in consumption order (8 loads outstanding)
  stageA(0, 0, 0); stageB(0, 0, 0); stageA(1, 0, 0); stageB(1, 0, 0);

  for (int kt = 0; kt < nt; ++kt) {
    const int c = kt & 1, sb = c ^ 1;
    const int st = (kt + 1 < nt) ? kt + 1 : 0;  // wrap keeps ledger exact
    u16x8 bf[4], af[8];
    // ==== phase 0: k-lo ====
    asm volatile("s_waitcnt vmcnt(4)" ::: "memory");
    asm volatile("s_barrier" ::: "memory");
    stageA(0, st, sb); stageB(0, st, sb);
#pragma unroll
    for (int ni = 0; ni < 4; ++ni) bf[ni] = readB(0, ni, c);
#pragma unroll
    for (int m = 0; m < 8; ++m) af[m] = readA(0, m, c);
    __builtin_amdgcn_s_setprio(1);
#pragma unroll
    for (int m = 0; m < 8; ++m)
#pragma unroll
      for (int ni = 0; ni < 4; ++ni)
        acc[m][ni] = MFMA(af[m], bf[ni], acc[m][ni]);
    __builtin_amdgcn_s_setprio(0);
    // ==== phase 1: k-hi ====
    asm volatile("s_waitcnt vmcnt(4)" ::: "memory");
    asm volatile("s_barrier" ::: "memory");
    stageA(1, st, sb); stageB(1, st, sb);
#pragma unroll
    for (int ni = 0; ni < 4; ++ni) bf[ni] = readB(1, ni, c);
#pragma unroll
    for (int m = 0; m < 8; ++m) af[m] = readA(1, m, c);
    __builtin_amdgcn_s_setprio(1);
#pragma unroll
    for (int m = 0; m < 8; ++m)
#pragma unroll
      for (int ni = 0; ni < 4; ++ni)
        acc[m][ni] = MFMA(af[m], bf[ni], acc[m][ni]);
    __builtin_amdgcn_s_setprio(0);
  }

  // ---- epilogue ----
  const int rb = (lane >> 4) << 2;
  const int cl = lane & 15;
  if (MODE == 0) {
    const int g = n_base + n0;
    const int which = g / DMODEL;
    const int col0 = g - which * DMODEL;
    if (which < 2) {
      ushort* dst = (which == 0) ? (ushort*)out0 : out1;
#pragma unroll
      for (int mi = 0; mi < 8; ++mi)
#pragma unroll
        for (int j = 0; j < 4; ++j) {
          const int l = m0 + wm * 128 + mi * 16 + rb + j;
          const size_t rbase = (size_t)l * DMODEL + col0 + wn * 64 + cl;
#pragma unroll
          for (int ni = 0; ni < 4; ++ni) dst[rbase + ni * 16] = f2h(acc[mi][ni][j]);
        }
    } else {
      // V block: bf16 + transpose through LDS, store directly as V^T[d][l]
      asm volatile("s_waitcnt vmcnt(0)" ::: "memory");  // drain wrapped stage DMAs
      asm volatile("s_barrier" ::: "memory");
      ushort* ldsT = &lds[0][0][0][0];  // 256*256 = 65536 ushorts exactly
#pragma unroll
      for (int mi = 0; mi < 8; ++mi)
#pragma unroll
        for (int j = 0; j < 4; ++j) {
          const int ml = wm * 128 + mi * 16 + rb + j;
#pragma unroll
          for (int ni = 0; ni < 4; ++ni)
            ldsT[(wn * 64 + ni * 16 + cl) * 256 + ml] = f2bf(acc[mi][ni][j]);
        }
      __syncthreads();
      const int tr = tid >> 2, tc = (tid & 3) * 64;
#pragma unroll
      for (int i = 0; i < 2; ++i) {
        const int dl = i * 128 + tr;
        ushort* dst = out2 + (size_t)(col0 + dl) * L_TOT + m0 + tc;
        const ushort* srcL = ldsT + dl * 256 + tc;
#pragma unroll
        for (int v = 0; v < 8; ++v)
          *(u16x8*)(dst + v * 8) = *(const u16x8*)(srcL + v * 8);
      }
    }
  } else if (MODE == 1) {
    float* outf = (float*)out0;
    const float* bias = (m0 < L_TXT) ? biasLo : biasHi;
    const int rofs = (m0 < L_TXT) ? L_IMG : -L_TXT;  // enc rows after img block
    float bv[4];
#pragma unroll
    for (int ni = 0; ni < 4; ++ni) bv[ni] = bias[n0 + wn * 64 + ni * 16 + cl];
#pragma unroll
    for (int mi = 0; mi < 8; ++mi)
#pragma unroll
      for (int j = 0; j < 4; ++j) {
        const int r = m0 + wm * 128 + mi * 16 + rb + j + rofs;
        const size_t rbase = (size_t)r * N + n0 + wn * 64 + cl;
#pragma unroll
        for (int ni = 0; ni < 4; ++ni) outf[rbase + ni * 16] = acc[mi][ni][j] + bv[ni];
      }
  } else if (MODE == 2) {
    // PV: normalize by fused-softmax row sum (biasLo = RS)
    ushort* outb = (ushort*)out0;
#pragma unroll
    for (int mi = 0; mi < 8; ++mi)
#pragma unroll
      for (int j = 0; j < 4; ++j) {
        const int r = m0 + wm * 128 + mi * 16 + rb + j;
        const float inv = 1.0f / biasLo[r];
        const size_t rbase = (size_t)r * N + n0 + wn * 64 + cl;
#pragma unroll
        for (int ni = 0; ni < 4; ++ni) outb[rbase + ni * 16] = f2h(acc[mi][ni][j] * inv);
      }
  } else {
    // S: write P = exp2((S - 32) * log2e) as bf16 (softmax exp fused; normalize in PV)
    ushort* outb = (ushort*)out0;
#pragma unroll
    for (int mi = 0; mi < 8; ++mi)
#pragma unroll
      for (int j = 0; j < 4; ++j) {
        const int r = m0 + wm * 128 + mi * 16 + rb + j;
        const size_t rbase = (size_t)r * N + n0 + wn * 64 + cl;
#pragma unroll
        for (int ni = 0; ni < 4; ++ni)
          outb[rbase + ni * 16] = f2bf(exp2f((acc[mi][ni][j] - S_SHIFT) * LOG2E));
      }
  }
}

// ---------------- fused RMSNorm + RoPE on merged Q,K [l][3072] fp16; f32 params --------
__global__ void norm_rope(ushort* __restrict__ Q, ushort* __restrict__ Kg,
                          const float* __restrict__ rope,
                          const float* __restrict__ qn, const float* __restrict__ kn,
                          const float* __restrict__ eqn, const float* __restrict__ ekn) {
  const int idx = (blockIdx.x << 2) + (threadIdx.x >> 6);  // (l*24 + h)
  const int lane = threadIdx.x & 63;
  const int h = idx % NH, l = idx / NH;
  const float* qsc = (l < L_TXT) ? eqn : qn;
  const float* ksc = (l < L_TXT) ? ekn : kn;
  const size_t base = (size_t)l * DMODEL + h * HD + (lane << 1);
  const f32x4 fcv = *(const f32x4*)(rope + ((size_t)l * 64 + lane) * 4);
  const float fa = fcv[0], fb = fcv[1], fc = fcv[2], fd = fcv[3];
  const float s0 = qsc[lane << 1], s1 = qsc[(lane << 1) + 1];
  const float t0 = ksc[lane << 1], t1 = ksc[(lane << 1) + 1];
  {
    const uint32_t qv = *(const uint32_t*)&Q[base];
    float x0 = h2f((ushort)(qv & 0xffff)), x1 = h2f((ushort)(qv >> 16));
    float ss = x0 * x0 + x1 * x1;
#pragma unroll
    for (int m = 1; m < 64; m <<= 1) ss += __shfl_xor(ss, m);
    const float r = rsqrtf(ss * (1.0f / 128.0f) + 1e-6f);
    x0 *= r * s0;
    x1 *= r * s1;
    const float o0 = (fa * x0 + fb * x1) * 0.08838834764831845f;
    const float o1 = (fc * x0 + fd * x1) * 0.08838834764831845f;
    *(uint32_t*)&Q[base] = (uint32_t)f2h(o0) | ((uint32_t)f2h(o1) << 16);
  }
  {
    const uint32_t kv = *(const uint32_t*)&Kg[base];
    float x0 = h2f((ushort)(kv & 0xffff)), x1 = h2f((ushort)(kv >> 16));
    float ss = x0 * x0 + x1 * x1;
#pragma unroll
    for (int m = 1; m < 64; m <<= 1) ss += __shfl_xor(ss, m);
    const float r = rsqrtf(ss * (1.0f / 128.0f) + 1e-6f);
    x0 *= r * t0;
    x1 *= r * t1;
    const float o0 = fa * x0 + fb * x1;
    const float o1 = fc * x0 + fd * x1;
    *(uint32_t*)&Kg[base] = (uint32_t)f2h(o0) | ((uint32_t)f2h(o1) << 16);
  }
}

extern "C" void kernel_launch(void* const* d_in, const int* in_sizes, int n_in,
                              void* d_out, int out_size, void* d_ws, size_t ws_size,
                              hipStream_t stream) {
  (void)in_sizes; (void)n_in; (void)out_size;
  const float* hidden  = (const float*)d_in[0];
  const float* enc     = (const float*)d_in[1];
  const float* rope    = (const float*)d_in[2];
  const float* W_iqkv  = (const float*)d_in[3];
  const float* W_eqkv  = (const float*)d_in[4];
  const float* W_iproj = (const float*)d_in[5];
  const float* b_iproj = (const float*)d_in[6];
  const float* W_eproj = (const float*)d_in[7];
  const float* b_eproj = (const float*)d_in[8];
  const float* qn  = (const float*)d_in[9];
  const float* kn  = (const float*)d_in[10];
  const float* eqn = (const float*)d_in[11];
  const float* ekn = (const float*)d_in[12];
  float* out = (float*)d_out;

  // ws layout (ushort units). Base footprint 127.4 MB:
  //   R0 = S region (42.5 MB): CF during QKV -> P (bf16) -> proj W^T pair
  //   QR (->AO), KR, VR (= V^T [3072][4608], written directly by QKV epilogue)
  // Big-ws path (>= 241 MB): two full QKV W^T beyond the base footprint.
  // RS (rowsums, 18 KB f32) lives in d_out (free between QKV and proj).
  const size_t SZ_S  = (size_t)L_TOT * L_TOT;
  const size_t SZ_LD = (size_t)L_TOT * DMODEL;
  const size_t SZ_WH = (size_t)L_TOT * DMODEL;       // half-W^T = [4608][3072]
  const size_t SZ_W  = (size_t)NQKV * DMODEL;        // full W^T = [9216][3072]
  ushort* R0  = (ushort*)d_ws;
  ushort* CF  = R0;                       // [enc; hidden] fp16 [4608][3072]
  ushort* S   = R0;                       // P (bf16) after S-GEMM
  ushort* QR  = R0 + SZ_S;
  ushort* KR  = QR + SZ_LD;
  ushort* VR  = KR + SZ_LD;               // V^T [3072][4608]
  ushort* AO  = QR;            // alias: QR dead after S GEMM
  ushort* WTe = (ushort*)out;  // enc half-W^T in d_out (fallback path)
  ushort* WTi = WTe + SZ_WH;   // img half-W^T in d_out (fallback path)
  ushort* WQe = VR + SZ_LD;    // full enc W^T (big-ws path)
  ushort* WQi = WQe + SZ_W;    // full img W^T (big-ws path)
  ushort* WPi = R0;                              // img proj W^T [3072][3072]
  ushort* WPe = R0 + (size_t)DMODEL * DMODEL;    // enc proj W^T
  float*  RS  = (float*)d_out;                   // row sums (consumed before proj)
  const bool big = ws_size >= (SZ_S + 3 * SZ_LD + 2 * SZ_W) * sizeof(ushort);

  dim3 blk(256);
  // inputs -> fp16, concatenated [enc; hidden]
  cvt_f32_f16<<<dim3(L_TXT * DMODEL / 8 / 256), blk, 0, stream>>>(enc, CF,
                                                                  L_TXT * DMODEL / 8);
  cvt_f32_f16<<<dim3(L_IMG * DMODEL / 8 / 256), blk, 0, stream>>>(
      hidden, CF + (size_t)L_TXT * DMODEL, L_IMG * DMODEL / 8);
  if (big) {
    // QKV: single merged dispatch, full N=9216 (648 blocks)
    tconv_w<<<dim3(NQKV / 64, DMODEL / 64), blk, 0, stream>>>(W_eqkv, NQKV, 0, WQe);
    tconv_w<<<dim3(NQKV / 64, DMODEL / 64), blk, 0, stream>>>(W_iqkv, NQKV, 0, WQi);
    gemm256<0><<<dim3(L_TOT / 256, NQKV / 256), dim3(512), 0, stream>>>(
        CF, DMODEL, WQe, WQi, DMODEL, NQKV, DMODEL,
        QR, KR, VR, nullptr, nullptr, 0);
  } else {
    // fallback: two 4608-col halves through d_out scratch
    for (int h = 0; h < 2; ++h) {
      const int c0 = h * 4608;
      tconv_w<<<dim3(72, 48), blk, 0, stream>>>(W_eqkv, NQKV, c0, WTe);
      tconv_w<<<dim3(72, 48), blk, 0, stream>>>(W_iqkv, NQKV, c0, WTi);
      gemm256<0><<<dim3(L_TOT / 256, 18), dim3(512), 0, stream>>>(
          CF, DMODEL, WTe, WTi, DMODEL, 4608, DMODEL,
          QR, KR, VR, nullptr, nullptr, c0);
    }
  }
  // per-head RMSNorm + RoPE (attn scale folded into Q)
  norm_rope<<<dim3(L_TOT * NH / 4), blk, 0, stream>>>(QR, KR, rope, qn, kn, eqn, ekn);
  // P = exp2((Q K^T - 32)*log2e) as bf16 (softmax exp fused into epilogue)
  gemm256<3><<<dim3(L_TOT / 256, L_TOT / 256), dim3(512), 0, stream>>>(
      QR, DMODEL, KR, KR, DMODEL, L_TOT, DMODEL, S, nullptr, nullptr,
      nullptr, nullptr, 0);
  // row sums of P (f32)
  rowsum<<<dim3(L_TOT), blk, 0, stream>>>(S, RS);
  // AO = (P @ V) / RS[row]  (bf16 MFMA; normalization fused into epilogue)
  gemm256<2><<<dim3(L_TOT / 256, DMODEL / 256), dim3(512), 0, stream>>>(
      S, L_TOT, VR, VR, L_TOT, DMODEL, L_TOT, AO, nullptr, nullptr,
      RS, nullptr, 0);
  // output projections: merged enc+img, per-block weight/bias select + row remap
  tconv_w<<<dim3(48, 48), blk, 0, stream>>>(W_iproj, DMODEL, 0, WPi);
  tconv_w<<<dim3(48, 48), blk, 0, stream>>>(W_eproj, DMODEL, 0, WPe);
  gemm256<1><<<dim3(L_TOT / 256, DMODEL / 256), dim3(512), 0, stream>>>(
      AO, DMODEL, WPe, WPi, DMODEL, DMODEL, DMODEL,
      out, nullptr, nullptr, b_eproj, b_iproj, 0);
}

// Round 22
// 824.078 us; speedup vs baseline: 1.0087x; 1.0087x over previous
//
#include <hip/hip_runtime.h>
#include <hip/hip_bf16.h>
#include <cstdint>

typedef __attribute__((ext_vector_type(8))) short u16x8;
typedef _Float16 f16_t;
typedef __attribute__((ext_vector_type(8))) f16_t f16x8;
typedef __attribute__((ext_vector_type(4))) float f32x4;

#define L_TOT 4608
#define L_TXT 512
#define L_IMG 4096
#define NH 24
#define HD 128
#define DMODEL 3072
#define NQKV 9216
#define LOG2E 1.44269504088896340736f
#define S_SHIFT 32.0f

__device__ __forceinline__ ushort f2h(float f) {
  union { f16_t h; ushort u; } c; c.h = (f16_t)f; return c.u;
}
__device__ __forceinline__ float h2f(ushort u) {
  union { ushort u; f16_t h; } c; c.u = u; return (float)c.h;
}
__device__ __forceinline__ ushort f2bf(float f) {
  union { float f; uint32_t i; } c; c.f = f;
  uint32_t i = c.i;
  return (ushort)((i + 0x7FFFu + ((i >> 16) & 1u)) >> 16);
}
__device__ __forceinline__ float bf2f(ushort u) {
  union { uint32_t i; float f; } c; c.i = ((uint32_t)u) << 16; return c.f;
}
__device__ __forceinline__ void gload16(const ushort* g, ushort* l) {
  __builtin_amdgcn_global_load_lds((const __attribute__((address_space(1))) void*)g,
                                   (__attribute__((address_space(3))) void*)l, 16, 0, 0);
}

// ------- cvt_f32_f16: elementwise f32 -> fp16, 8 elems/thread ---------------------------
__global__ void cvt_f32_f16(const float* __restrict__ src, ushort* __restrict__ dst,
                            int n8) {
  const int i = blockIdx.x * 256 + threadIdx.x;
  if (i >= n8) return;
  const f32x4 a = *(const f32x4*)(src + (size_t)i * 8);
  const f32x4 b = *(const f32x4*)(src + (size_t)i * 8 + 4);
  alignas(16) ushort o[8];
#pragma unroll
  for (int j = 0; j < 4; ++j) { o[j] = f2h(a[j]); o[4 + j] = f2h(b[j]); }
  *(u16x8*)(dst + (size_t)i * 8) = *(const u16x8*)o;
}

// ------- tconv_w: f32 weight [3072][C], col-slice c0..c0+Nsl -> fp16 [Nsl][3072] --------
__global__ void tconv_w(const float* __restrict__ src, int C, int c0,
                        ushort* __restrict__ dst) {
  __shared__ ushort tile[64][72];
  const int nb = blockIdx.x << 6, kb = blockIdx.y << 6;
  const int t = threadIdx.x;
  const int lr = t >> 2, lc = (t & 3) << 4;
  const float* sp = src + (size_t)(kb + lr) * C + c0 + nb + lc;
  const f32x4 v0 = *(const f32x4*)sp;
  const f32x4 v1 = *(const f32x4*)(sp + 4);
  const f32x4 v2 = *(const f32x4*)(sp + 8);
  const f32x4 v3 = *(const f32x4*)(sp + 12);
#pragma unroll
  for (int i = 0; i < 4; ++i) {
    tile[lr][lc + i]      = f2h(v0[i]);
    tile[lr][lc + 4 + i]  = f2h(v1[i]);
    tile[lr][lc + 8 + i]  = f2h(v2[i]);
    tile[lr][lc + 12 + i] = f2h(v3[i]);
  }
  __syncthreads();
  const int cl = t & 63, rb = (t >> 6) << 4;
  alignas(16) ushort o[16];
#pragma unroll
  for (int i = 0; i < 16; ++i) o[i] = tile[rb + i][cl];
  ushort* dp = dst + (size_t)(nb + cl) * DMODEL + kb + rb;
  *(u16x8*)dp       = *(const u16x8*)o;
  *(u16x8*)(dp + 8) = *(const u16x8*)(o + 8);
}

// ------- tconv_h: 16-bit src [R][C] -> dst [C][R] (V -> V^T, dtype-agnostic) -----------
__global__ void tconv_h(const ushort* __restrict__ src, ushort* __restrict__ dst,
                        int R, int C) {
  __shared__ ushort tile[64][72];
  const int r0 = blockIdx.y << 6, c0 = blockIdx.x << 6;
  const int t = threadIdx.x;
  const int lr = t >> 2, lc = (t & 3) << 4;
  const ushort* sp = src + (size_t)(r0 + lr) * C + c0 + lc;
  const u16x8 v0 = *(const u16x8*)sp;
  const u16x8 v1 = *(const u16x8*)(sp + 8);
#pragma unroll
  for (int i = 0; i < 8; ++i) {
    tile[lr][lc + i]     = ((const ushort*)&v0)[i];
    tile[lr][lc + 8 + i] = ((const ushort*)&v1)[i];
  }
  __syncthreads();
  const int cl = t & 63, rb = (t >> 6) << 4;
  alignas(16) ushort o[16];
#pragma unroll
  for (int i = 0; i < 16; ++i) o[i] = tile[rb + i][cl];
  ushort* dp = dst + (size_t)(c0 + cl) * R + r0 + rb;
  *(u16x8*)dp       = *(const u16x8*)o;
  *(u16x8*)(dp + 8) = *(const u16x8*)(o + 8);
}

// ------- rowsum: per-row f32 sum of bf16 P[4608][4608] ---------------------------------
__global__ void rowsum(const ushort* __restrict__ P, float* __restrict__ RS) {
  const int r = blockIdx.x, tid = threadIdx.x;
  const ushort* Pr = P + (size_t)r * L_TOT;
  float s = 0.f;
#pragma unroll
  for (int j = 0; j < 18; ++j) s += bf2f(Pr[tid + (j << 8)]);
#pragma unroll
  for (int o = 1; o < 64; o <<= 1) s += __shfl_xor(s, o);
  __shared__ float reds[4];
  const int wave = tid >> 6, lane = tid & 63;
  if (lane == 0) reds[wave] = s;
  __syncthreads();
  if (tid == 0) RS[r] = reds[0] + reds[1] + reds[2] + reds[3];
}

// =========== gemm256: 256x256, BK=64, 8 waves, 2-phase counted schedule ================
// Body identical to round-18/20 best. Per-block operand select for merged enc+img
// dispatches (m0 < 512 -> BtLo/biasLo). MODE 2 uses bf16 MFMA (P, V^T are bf16).
// Epilogues: MODE 0 qkv scatter (Q,K fp16; V -> bf16 row-major, NO LDS transpose —
// r21's fused transpose caused 4.1e6 bank conflicts); MODE 1 f32 out + bias (merged
// proj, row remap); MODE 2 fp16 out scaled by 1/RS[row] (fused softmax normalize);
// MODE 3 bf16 exp2((acc-32)*log2e) (fused softmax exp).
template <int MODE>
__global__ __launch_bounds__(512, 2) void gemm256(
    const ushort* __restrict__ A, int lda,
    const ushort* __restrict__ BtLo, const ushort* __restrict__ BtHi, int ldb,
    int N, int K, void* __restrict__ out0, ushort* __restrict__ out1,
    ushort* __restrict__ out2, const float* __restrict__ biasLo,
    const float* __restrict__ biasHi, int n_base) {
  __shared__ __align__(16) ushort lds[2][2][2][8192];  // [buf][khalf][mat][256*32]
  int lin = blockIdx.y * gridDim.x + blockIdx.x;
  {
    const int nwg = gridDim.x * gridDim.y;
    const int q8 = nwg >> 3, r8 = nwg & 7;
    const int xcd = lin & 7, idx = lin >> 3;
    lin = (xcd < r8 ? xcd * (q8 + 1) : r8 * (q8 + 1) + (xcd - r8) * q8) + idx;
  }
  const int m0 = (lin % gridDim.x) << 8, n0 = (lin / gridDim.x) << 8;
  const ushort* Bt = (m0 < L_TXT) ? BtLo : BtHi;
  const int tid = threadIdx.x, w = tid >> 6, lane = tid & 63;
  const int wm = w >> 2, wn = w & 3;
  const int lr = lane & 15, g4 = lane >> 4;
  const int srow = lane >> 2;
  const int soff = 8 * ((lane & 3) ^ ((lane >> 3) & 3));  // k-elems within half
  f32x4 acc[8][4];
#pragma unroll
  for (int a = 0; a < 8; ++a)
#pragma unroll
    for (int b = 0; b < 4; ++b) acc[a][b] = (f32x4){0.f, 0.f, 0.f, 0.f};
  const int nt = K >> 6;

  auto stageA = [&](int h, int kt, int b) {
#pragma unroll
    for (int i = 0; i < 2; ++i) {
      const int j = w * 2 + i;
      gload16(A + (size_t)(m0 + 16 * j + srow) * lda + (kt << 6) + 32 * h + soff,
              &lds[b][h][0][j * 512]);
    }
  };
  auto stageB = [&](int h, int kt, int b) {
#pragma unroll
    for (int i = 0; i < 2; ++i) {
      const int j = w * 2 + i;
      gload16(Bt + (size_t)(n0 + 16 * j + srow) * ldb + (kt << 6) + 32 * h + soff,
              &lds[b][h][1][j * 512]);
    }
  };
  auto readA = [&](int h, int mi, int b) -> u16x8 {
    const int row = wm * 128 + mi * 16 + lr;
    const int byte = row * 64 + ((g4 ^ ((row >> 1) & 3)) << 4);
    return *(const u16x8*)((const char*)&lds[b][h][0][0] + byte);
  };
  auto readB = [&](int h, int ni, int b) -> u16x8 {
    const int row = wn * 64 + ni * 16 + lr;
    const int byte = row * 64 + ((g4 ^ ((row >> 1) & 3)) << 4);
    return *(const u16x8*)((const char*)&lds[b][h][1][0] + byte);
  };
  auto MFMA = [&](u16x8 a, u16x8 b, f32x4 c) -> f32x4 {
    if constexpr (MODE == 2)
      return __builtin_amdgcn_mfma_f32_16x16x32_bf16(a, b, c, 0, 0, 0);
    else
      return __builtin_amdgcn_mfma_f32_16x16x32_f16(
          __builtin_bit_cast(f16x8, a), __builtin_bit_cast(f16x8, b), c, 0, 0, 0);
  };

  // prologue: stage tile 0 in consumption order (8 loads outstanding)
  stageA(0, 0, 0); stageB(0, 0, 0); stageA(1, 0, 0); stageB(1, 0, 0);

  for (int kt = 0; kt < nt; ++kt) {
    const int c = kt & 1, sb = c ^ 1;
    const int st = (kt + 1 < nt) ? kt + 1 : 0;  // wrap keeps ledger exact
    u16x8 bf[4], af[8];
    // ==== phase 0: k-lo ====
    asm volatile("s_waitcnt vmcnt(4)" ::: "memory");
    asm volatile("s_barrier" ::: "memory");
    stageA(0, st, sb); stageB(0, st, sb);
#pragma unroll
    for (int ni = 0; ni < 4; ++ni) bf[ni] = readB(0, ni, c);
#pragma unroll
    for (int m = 0; m < 8; ++m) af[m] = readA(0, m, c);
    __builtin_amdgcn_s_setprio(1);
#pragma unroll
    for (int m = 0; m < 8; ++m)
#pragma unroll
      for (int ni = 0; ni < 4; ++ni)
        acc[m][ni] = MFMA(af[m], bf[ni], acc[m][ni]);
    __builtin_amdgcn_s_setprio(0);
    // ==== phase 1: k-hi ====
    asm volatile("s_waitcnt vmcnt(4)" ::: "memory");
    asm volatile("s_barrier" ::: "memory");
    stageA(1, st, sb); stageB(1, st, sb);
#pragma unroll
    for (int ni = 0; ni < 4; ++ni) bf[ni] = readB(1, ni, c);
#pragma unroll
    for (int m = 0; m < 8; ++m) af[m] = readA(1, m, c);
    __builtin_amdgcn_s_setprio(1);
#pragma unroll
    for (int m = 0; m < 8; ++m)
#pragma unroll
      for (int ni = 0; ni < 4; ++ni)
        acc[m][ni] = MFMA(af[m], bf[ni], acc[m][ni]);
    __builtin_amdgcn_s_setprio(0);
  }

  // ---- epilogue ----
  const int rb = (lane >> 4) << 2;
  const int cl = lane & 15;
  if (MODE == 0) {
    const int g = n_base + n0;
    const int which = g / DMODEL;
    const int col0 = g - which * DMODEL;
    ushort* dst = (which == 0) ? (ushort*)out0 : (which == 1) ? out1 : out2;
#pragma unroll
    for (int mi = 0; mi < 8; ++mi)
#pragma unroll
      for (int j = 0; j < 4; ++j) {
        const int l = m0 + wm * 128 + mi * 16 + rb + j;
        const size_t rbase = (size_t)l * DMODEL + col0 + wn * 64 + cl;
        if (which < 2) {
#pragma unroll
          for (int ni = 0; ni < 4; ++ni) dst[rbase + ni * 16] = f2h(acc[mi][ni][j]);
        } else {
          // V: bf16 row-major (transposed later by conflict-free tconv_h)
#pragma unroll
          for (int ni = 0; ni < 4; ++ni) dst[rbase + ni * 16] = f2bf(acc[mi][ni][j]);
        }
      }
  } else if (MODE == 1) {
    float* outf = (float*)out0;
    const float* bias = (m0 < L_TXT) ? biasLo : biasHi;
    const int rofs = (m0 < L_TXT) ? L_IMG : -L_TXT;  // enc rows after img block
    float bv[4];
#pragma unroll
    for (int ni = 0; ni < 4; ++ni) bv[ni] = bias[n0 + wn * 64 + ni * 16 + cl];
#pragma unroll
    for (int mi = 0; mi < 8; ++mi)
#pragma unroll
      for (int j = 0; j < 4; ++j) {
        const int r = m0 + wm * 128 + mi * 16 + rb + j + rofs;
        const size_t rbase = (size_t)r * N + n0 + wn * 64 + cl;
#pragma unroll
        for (int ni = 0; ni < 4; ++ni) outf[rbase + ni * 16] = acc[mi][ni][j] + bv[ni];
      }
  } else if (MODE == 2) {
    // PV: normalize by fused-softmax row sum (biasLo = RS)
    ushort* outb = (ushort*)out0;
#pragma unroll
    for (int mi = 0; mi < 8; ++mi)
#pragma unroll
      for (int j = 0; j < 4; ++j) {
        const int r = m0 + wm * 128 + mi * 16 + rb + j;
        const float inv = 1.0f / biasLo[r];
        const size_t rbase = (size_t)r * N + n0 + wn * 64 + cl;
#pragma unroll
        for (int ni = 0; ni < 4; ++ni) outb[rbase + ni * 16] = f2h(acc[mi][ni][j] * inv);
      }
  } else {
    // S: write P = exp2((S - 32) * log2e) as bf16 (softmax exp fused; normalize in PV)
    ushort* outb = (ushort*)out0;
#pragma unroll
    for (int mi = 0; mi < 8; ++mi)
#pragma unroll
      for (int j = 0; j < 4; ++j) {
        const int r = m0 + wm * 128 + mi * 16 + rb + j;
        const size_t rbase = (size_t)r * N + n0 + wn * 64 + cl;
#pragma unroll
        for (int ni = 0; ni < 4; ++ni)
          outb[rbase + ni * 16] = f2bf(exp2f((acc[mi][ni][j] - S_SHIFT) * LOG2E));
      }
  }
}

// ---------------- fused RMSNorm + RoPE on merged Q,K [l][3072] fp16; f32 params --------
__global__ void norm_rope(ushort* __restrict__ Q, ushort* __restrict__ Kg,
                          const float* __restrict__ rope,
                          const float* __restrict__ qn, const float* __restrict__ kn,
                          const float* __restrict__ eqn, const float* __restrict__ ekn) {
  const int idx = (blockIdx.x << 2) + (threadIdx.x >> 6);  // (l*24 + h)
  const int lane = threadIdx.x & 63;
  const int h = idx % NH, l = idx / NH;
  const float* qsc = (l < L_TXT) ? eqn : qn;
  const float* ksc = (l < L_TXT) ? ekn : kn;
  const size_t base = (size_t)l * DMODEL + h * HD + (lane << 1);
  const f32x4 fcv = *(const f32x4*)(rope + ((size_t)l * 64 + lane) * 4);
  const float fa = fcv[0], fb = fcv[1], fc = fcv[2], fd = fcv[3];
  const float s0 = qsc[lane << 1], s1 = qsc[(lane << 1) + 1];
  const float t0 = ksc[lane << 1], t1 = ksc[(lane << 1) + 1];
  {
    const uint32_t qv = *(const uint32_t*)&Q[base];
    float x0 = h2f((ushort)(qv & 0xffff)), x1 = h2f((ushort)(qv >> 16));
    float ss = x0 * x0 + x1 * x1;
#pragma unroll
    for (int m = 1; m < 64; m <<= 1) ss += __shfl_xor(ss, m);
    const float r = rsqrtf(ss * (1.0f / 128.0f) + 1e-6f);
    x0 *= r * s0;
    x1 *= r * s1;
    const float o0 = (fa * x0 + fb * x1) * 0.08838834764831845f;
    const float o1 = (fc * x0 + fd * x1) * 0.08838834764831845f;
    *(uint32_t*)&Q[base] = (uint32_t)f2h(o0) | ((uint32_t)f2h(o1) << 16);
  }
  {
    const uint32_t kv = *(const uint32_t*)&Kg[base];
    float x0 = h2f((ushort)(kv & 0xffff)), x1 = h2f((ushort)(kv >> 16));
    float ss = x0 * x0 + x1 * x1;
#pragma unroll
    for (int m = 1; m < 64; m <<= 1) ss += __shfl_xor(ss, m);
    const float r = rsqrtf(ss * (1.0f / 128.0f) + 1e-6f);
    x0 *= r * t0;
    x1 *= r * t1;
    const float o0 = fa * x0 + fb * x1;
    const float o1 = fc * x0 + fd * x1;
    *(uint32_t*)&Kg[base] = (uint32_t)f2h(o0) | ((uint32_t)f2h(o1) << 16);
  }
}

extern "C" void kernel_launch(void* const* d_in, const int* in_sizes, int n_in,
                              void* d_out, int out_size, void* d_ws, size_t ws_size,
                              hipStream_t stream) {
  (void)in_sizes; (void)n_in; (void)out_size;
  const float* hidden  = (const float*)d_in[0];
  const float* enc     = (const float*)d_in[1];
  const float* rope    = (const float*)d_in[2];
  const float* W_iqkv  = (const float*)d_in[3];
  const float* W_eqkv  = (const float*)d_in[4];
  const float* W_iproj = (const float*)d_in[5];
  const float* b_iproj = (const float*)d_in[6];
  const float* W_eproj = (const float*)d_in[7];
  const float* b_eproj = (const float*)d_in[8];
  const float* qn  = (const float*)d_in[9];
  const float* kn  = (const float*)d_in[10];
  const float* eqn = (const float*)d_in[11];
  const float* ekn = (const float*)d_in[12];
  float* out = (float*)d_out;

  // ws layout (ushort units). Base footprint 127.4 MB:
  //   R0 = S region (42.5 MB): CF during QKV -> P (bf16) -> proj W^T pair
  //   QR (->AO), KR (->VT after S GEMM), VR (V row-major bf16)
  // Big-ws path (>= 241 MB): two full QKV W^T beyond the base footprint.
  // RS (rowsums, 18 KB f32) lives in d_out (free until proj writes it).
  const size_t SZ_S  = (size_t)L_TOT * L_TOT;
  const size_t SZ_LD = (size_t)L_TOT * DMODEL;
  const size_t SZ_WH = (size_t)L_TOT * DMODEL;       // half-W^T = [4608][3072]
  const size_t SZ_W  = (size_t)NQKV * DMODEL;        // full W^T = [9216][3072]
  ushort* R0  = (ushort*)d_ws;
  ushort* CF  = R0;                       // [enc; hidden] fp16 [4608][3072]
  ushort* S   = R0;                       // P (bf16) after S-GEMM
  ushort* QR  = R0 + SZ_S;
  ushort* KR  = QR + SZ_LD;
  ushort* VR  = KR + SZ_LD;               // V row-major bf16 [4608][3072]
  ushort* VT  = KR;            // alias: KR dead after S GEMM; V^T bf16 [3072][4608]
  ushort* AO  = QR;            // alias: QR dead after S GEMM
  ushort* WTe = (ushort*)out;  // enc half-W^T in d_out (fallback path)
  ushort* WTi = WTe + SZ_WH;   // img half-W^T in d_out (fallback path)
  ushort* WQe = VR + SZ_LD;    // full enc W^T (big-ws path)
  ushort* WQi = WQe + SZ_W;    // full img W^T (big-ws path)
  ushort* WPi = R0;                              // img proj W^T [3072][3072]
  ushort* WPe = R0 + (size_t)DMODEL * DMODEL;    // enc proj W^T
  float*  RS  = (float*)d_out;                   // row sums (consumed before proj)
  const bool big = ws_size >= (SZ_S + 3 * SZ_LD + 2 * SZ_W) * sizeof(ushort);

  dim3 blk(256);
  // inputs -> fp16, concatenated [enc; hidden]
  cvt_f32_f16<<<dim3(L_TXT * DMODEL / 8 / 256), blk, 0, stream>>>(enc, CF,
                                                                  L_TXT * DMODEL / 8);
  cvt_f32_f16<<<dim3(L_IMG * DMODEL / 8 / 256), blk, 0, stream>>>(
      hidden, CF + (size_t)L_TXT * DMODEL, L_IMG * DMODEL / 8);
  if (big) {
    // QKV: single merged dispatch, full N=9216 (648 blocks)
    tconv_w<<<dim3(NQKV / 64, DMODEL / 64), blk, 0, stream>>>(W_eqkv, NQKV, 0, WQe);
    tconv_w<<<dim3(NQKV / 64, DMODEL / 64), blk, 0, stream>>>(W_iqkv, NQKV, 0, WQi);
    gemm256<0><<<dim3(L_TOT / 256, NQKV / 256), dim3(512), 0, stream>>>(
        CF, DMODEL, WQe, WQi, DMODEL, NQKV, DMODEL,
        QR, KR, VR, nullptr, nullptr, 0);
  } else {
    // fallback: two 4608-col halves through d_out scratch
    for (int h = 0; h < 2; ++h) {
      const int c0 = h * 4608;
      tconv_w<<<dim3(72, 48), blk, 0, stream>>>(W_eqkv, NQKV, c0, WTe);
      tconv_w<<<dim3(72, 48), blk, 0, stream>>>(W_iqkv, NQKV, c0, WTi);
      gemm256<0><<<dim3(L_TOT / 256, 18), dim3(512), 0, stream>>>(
          CF, DMODEL, WTe, WTi, DMODEL, 4608, DMODEL,
          QR, KR, VR, nullptr, nullptr, c0);
    }
  }
  // per-head RMSNorm + RoPE (attn scale folded into Q)
  norm_rope<<<dim3(L_TOT * NH / 4), blk, 0, stream>>>(QR, KR, rope, qn, kn, eqn, ekn);
  // P = exp2((Q K^T - 32)*log2e) as bf16 (softmax exp fused into epilogue)
  gemm256<3><<<dim3(L_TOT / 256, L_TOT / 256), dim3(512), 0, stream>>>(
      QR, DMODEL, KR, KR, DMODEL, L_TOT, DMODEL, S, nullptr, nullptr,
      nullptr, nullptr, 0);
  // row sums of P (f32)
  rowsum<<<dim3(L_TOT), blk, 0, stream>>>(S, RS);
  // V^T (bf16 [3072][4608]) — conflict-free tiled transpose (KR region now free)
  tconv_h<<<dim3(48, 72), blk, 0, stream>>>(VR, VT, L_TOT, DMODEL);
  // AO = (P @ V) / RS[row]  (bf16 MFMA; normalization fused into epilogue)
  gemm256<2><<<dim3(L_TOT / 256, DMODEL / 256), dim3(512), 0, stream>>>(
      S, L_TOT, VT, VT, L_TOT, DMODEL, L_TOT, AO, nullptr, nullptr,
      RS, nullptr, 0);
  // output projections: merged enc+img, per-block weight/bias select + row remap
  tconv_w<<<dim3(48, 48), blk, 0, stream>>>(W_iproj, DMODEL, 0, WPi);
  tconv_w<<<dim3(48, 48), blk, 0, stream>>>(W_eproj, DMODEL, 0, WPe);
  gemm256<1><<<dim3(L_TOT / 256, DMODEL / 256), dim3(512), 0, stream>>>(
      AO, DMODEL, WPe, WPi, DMODEL, DMODEL, DMODEL,
      out, nullptr, nullptr, b_eproj, b_iproj, 0);
}

// Round 23
// 819.652 us; speedup vs baseline: 1.0141x; 1.0054x over previous
//
#include <hip/hip_runtime.h>
#include <hip/hip_bf16.h>
#include <cstdint>

typedef __attribute__((ext_vector_type(8))) short u16x8;
typedef _Float16 f16_t;
typedef __attribute__((ext_vector_type(8))) f16_t f16x8;
typedef __attribute__((ext_vector_type(4))) float f32x4;

#define L_TOT 4608
#define L_TXT 512
#define L_IMG 4096
#define NH 24
#define HD 128
#define DMODEL 3072
#define NQKV 9216
#define LOG2E 1.44269504088896340736f
#define S_SHIFT 32.0f

__device__ __forceinline__ ushort f2h(float f) {
  union { f16_t h; ushort u; } c; c.h = (f16_t)f; return c.u;
}
__device__ __forceinline__ float h2f(ushort u) {
  union { ushort u; f16_t h; } c; c.u = u; return (float)c.h;
}
__device__ __forceinline__ ushort f2bf(float f) {
  union { float f; uint32_t i; } c; c.f = f;
  uint32_t i = c.i;
  return (ushort)((i + 0x7FFFu + ((i >> 16) & 1u)) >> 16);
}
__device__ __forceinline__ float bf2f(ushort u) {
  union { uint32_t i; float f; } c; c.i = ((uint32_t)u) << 16; return c.f;
}
__device__ __forceinline__ void gload16(const ushort* g, ushort* l) {
  __builtin_amdgcn_global_load_lds((const __attribute__((address_space(1))) void*)g,
                                   (__attribute__((address_space(3))) void*)l, 16, 0, 0);
}

// ------- cvt_f32_f16: elementwise f32 -> fp16, 8 elems/thread ---------------------------
__global__ void cvt_f32_f16(const float* __restrict__ src, ushort* __restrict__ dst,
                            int n8) {
  const int i = blockIdx.x * 256 + threadIdx.x;
  if (i >= n8) return;
  const f32x4 a = *(const f32x4*)(src + (size_t)i * 8);
  const f32x4 b = *(const f32x4*)(src + (size_t)i * 8 + 4);
  alignas(16) ushort o[8];
#pragma unroll
  for (int j = 0; j < 4; ++j) { o[j] = f2h(a[j]); o[4 + j] = f2h(b[j]); }
  *(u16x8*)(dst + (size_t)i * 8) = *(const u16x8*)o;
}

// ------- tconv_w: f32 weight [3072][C], col-slice c0..c0+Nsl -> fp16 [Nsl][3072] --------
__global__ void tconv_w(const float* __restrict__ src, int C, int c0,
                        ushort* __restrict__ dst) {
  __shared__ ushort tile[64][72];
  const int nb = blockIdx.x << 6, kb = blockIdx.y << 6;
  const int t = threadIdx.x;
  const int lr = t >> 2, lc = (t & 3) << 4;
  const float* sp = src + (size_t)(kb + lr) * C + c0 + nb + lc;
  const f32x4 v0 = *(const f32x4*)sp;
  const f32x4 v1 = *(const f32x4*)(sp + 4);
  const f32x4 v2 = *(const f32x4*)(sp + 8);
  const f32x4 v3 = *(const f32x4*)(sp + 12);
#pragma unroll
  for (int i = 0; i < 4; ++i) {
    tile[lr][lc + i]      = f2h(v0[i]);
    tile[lr][lc + 4 + i]  = f2h(v1[i]);
    tile[lr][lc + 8 + i]  = f2h(v2[i]);
    tile[lr][lc + 12 + i] = f2h(v3[i]);
  }
  __syncthreads();
  const int cl = t & 63, rb = (t >> 6) << 4;
  alignas(16) ushort o[16];
#pragma unroll
  for (int i = 0; i < 16; ++i) o[i] = tile[rb + i][cl];
  ushort* dp = dst + (size_t)(nb + cl) * DMODEL + kb + rb;
  *(u16x8*)dp       = *(const u16x8*)o;
  *(u16x8*)(dp + 8) = *(const u16x8*)(o + 8);
}

// ------- tconv_h: 16-bit src [R][C] -> dst [C][R] (fallback V -> V^T) ------------------
__global__ void tconv_h(const ushort* __restrict__ src, ushort* __restrict__ dst,
                        int R, int C) {
  __shared__ ushort tile[64][72];
  const int r0 = blockIdx.y << 6, c0 = blockIdx.x << 6;
  const int t = threadIdx.x;
  const int lr = t >> 2, lc = (t & 3) << 4;
  const ushort* sp = src + (size_t)(r0 + lr) * C + c0 + lc;
  const u16x8 v0 = *(const u16x8*)sp;
  const u16x8 v1 = *(const u16x8*)(sp + 8);
#pragma unroll
  for (int i = 0; i < 8; ++i) {
    tile[lr][lc + i]     = ((const ushort*)&v0)[i];
    tile[lr][lc + 8 + i] = ((const ushort*)&v1)[i];
  }
  __syncthreads();
  const int cl = t & 63, rb = (t >> 6) << 4;
  alignas(16) ushort o[16];
#pragma unroll
  for (int i = 0; i < 16; ++i) o[i] = tile[rb + i][cl];
  ushort* dp = dst + (size_t)(c0 + cl) * R + r0 + rb;
  *(u16x8*)dp       = *(const u16x8*)o;
  *(u16x8*)(dp + 8) = *(const u16x8*)(o + 8);
}

// ------- rowsum: per-row f32 sum of bf16 P[4608][4608] ---------------------------------
__global__ void rowsum(const ushort* __restrict__ P, float* __restrict__ RS) {
  const int r = blockIdx.x, tid = threadIdx.x;
  const ushort* Pr = P + (size_t)r * L_TOT;
  float s = 0.f;
#pragma unroll
  for (int j = 0; j < 18; ++j) s += bf2f(Pr[tid + (j << 8)]);
#pragma unroll
  for (int o = 1; o < 64; o <<= 1) s += __shfl_xor(s, o);
  __shared__ float reds[4];
  const int wave = tid >> 6, lane = tid & 63;
  if (lane == 0) reds[wave] = s;
  __syncthreads();
  if (tid == 0) RS[r] = reds[0] + reds[1] + reds[2] + reds[3];
}

// =========== gemm256: 256x256, BK=64, 8 waves, 2-phase counted schedule ================
// Body identical to round-18/22 best (MfmaUtil ~41%, conflicts 0).
// Operand selects: B by m0 (m0 < 512 -> BtLo, merged enc+img over M);
//                  A by n0 when MODE==4 (n0 < 512 -> A, else A2: V^T GEMM where the
//                  weight differs per output column block).
// MODE: 0 qkv scatter (Q,K fp16; V bf16 row-major, fallback path only)
//       1 f32 out + bias (merged proj, enc-row remap)
//       2 fp16 out * 1/RS[row] (PV, bf16 MFMA, fused softmax normalize)
//       3 bf16 exp2((acc-32)*log2e) (S, fused softmax exp)
//       4 bf16 plain out (direct V^T = Wv^T @ CF^T, no transpose kernel)
template <int MODE>
__global__ __launch_bounds__(512, 2) void gemm256(
    const ushort* __restrict__ A, const ushort* __restrict__ A2, int lda,
    const ushort* __restrict__ BtLo, const ushort* __restrict__ BtHi, int ldb,
    int N, int K, void* __restrict__ out0, ushort* __restrict__ out1,
    ushort* __restrict__ out2, const float* __restrict__ biasLo,
    const float* __restrict__ biasHi, int n_base) {
  __shared__ __align__(16) ushort lds[2][2][2][8192];  // [buf][khalf][mat][256*32]
  int lin = blockIdx.y * gridDim.x + blockIdx.x;
  {
    const int nwg = gridDim.x * gridDim.y;
    const int q8 = nwg >> 3, r8 = nwg & 7;
    const int xcd = lin & 7, idx = lin >> 3;
    lin = (xcd < r8 ? xcd * (q8 + 1) : r8 * (q8 + 1) + (xcd - r8) * q8) + idx;
  }
  const int m0 = (lin % gridDim.x) << 8, n0 = (lin / gridDim.x) << 8;
  const ushort* Bt  = (m0 < L_TXT) ? BtLo : BtHi;
  const ushort* Aop = (MODE == 4 && n0 >= L_TXT) ? A2 : A;
  const int tid = threadIdx.x, w = tid >> 6, lane = tid & 63;
  const int wm = w >> 2, wn = w & 3;
  const int lr = lane & 15, g4 = lane >> 4;
  const int srow = lane >> 2;
  const int soff = 8 * ((lane & 3) ^ ((lane >> 3) & 3));  // k-elems within half
  f32x4 acc[8][4];
#pragma unroll
  for (int a = 0; a < 8; ++a)
#pragma unroll
    for (int b = 0; b < 4; ++b) acc[a][b] = (f32x4){0.f, 0.f, 0.f, 0.f};
  const int nt = K >> 6;

  auto stageA = [&](int h, int kt, int b) {
#pragma unroll
    for (int i = 0; i < 2; ++i) {
      const int j = w * 2 + i;
      gload16(Aop + (size_t)(m0 + 16 * j + srow) * lda + (kt << 6) + 32 * h + soff,
              &lds[b][h][0][j * 512]);
    }
  };
  auto stageB = [&](int h, int kt, int b) {
#pragma unroll
    for (int i = 0; i < 2; ++i) {
      const int j = w * 2 + i;
      gload16(Bt + (size_t)(n0 + 16 * j + srow) * ldb + (kt << 6) + 32 * h + soff,
              &lds[b][h][1][j * 512]);
    }
  };
  auto readA = [&](int h, int mi, int b) -> u16x8 {
    const int row = wm * 128 + mi * 16 + lr;
    const int byte = row * 64 + ((g4 ^ ((row >> 1) & 3)) << 4);
    return *(const u16x8*)((const char*)&lds[b][h][0][0] + byte);
  };
  auto readB = [&](int h, int ni, int b) -> u16x8 {
    const int row = wn * 64 + ni * 16 + lr;
    const int byte = row * 64 + ((g4 ^ ((row >> 1) & 3)) << 4);
    return *(const u16x8*)((const char*)&lds[b][h][1][0] + byte);
  };
  auto MFMA = [&](u16x8 a, u16x8 b, f32x4 c) -> f32x4 {
    if constexpr (MODE == 2)
      return __builtin_amdgcn_mfma_f32_16x16x32_bf16(a, b, c, 0, 0, 0);
    else
      return __builtin_amdgcn_mfma_f32_16x16x32_f16(
          __builtin_bit_cast(f16x8, a), __builtin_bit_cast(f16x8, b), c, 0, 0, 0);
  };

  // prologue: stage tile 0 in consumption order (8 loads outstanding)
  stageA(0, 0, 0); stageB(0, 0, 0); stageA(1, 0, 0); stageB(1, 0, 0);

  for (int kt = 0; kt < nt; ++kt) {
    const int c = kt & 1, sb = c ^ 1;
    const int st = (kt + 1 < nt) ? kt + 1 : 0;  // wrap keeps ledger exact
    u16x8 bf[4], af[8];
    // ==== phase 0: k-lo ====
    asm volatile("s_waitcnt vmcnt(4)" ::: "memory");
    asm volatile("s_barrier" ::: "memory");
    stageA(0, st, sb); stageB(0, st, sb);
#pragma unroll
    for (int ni = 0; ni < 4; ++ni) bf[ni] = readB(0, ni, c);
#pragma unroll
    for (int m = 0; m < 8; ++m) af[m] = readA(0, m, c);
    __builtin_amdgcn_s_setprio(1);
#pragma unroll
    for (int m = 0; m < 8; ++m)
#pragma unroll
      for (int ni = 0; ni < 4; ++ni)
        acc[m][ni] = MFMA(af[m], bf[ni], acc[m][ni]);
    __builtin_amdgcn_s_setprio(0);
    // ==== phase 1: k-hi ====
    asm volatile("s_waitcnt vmcnt(4)" ::: "memory");
    asm volatile("s_barrier" ::: "memory");
    stageA(1, st, sb); stageB(1, st, sb);
#pragma unroll
    for (int ni = 0; ni < 4; ++ni) bf[ni] = readB(1, ni, c);
#pragma unroll
    for (int m = 0; m < 8; ++m) af[m] = readA(1, m, c);
    __builtin_amdgcn_s_setprio(1);
#pragma unroll
    for (int m = 0; m < 8; ++m)
#pragma unroll
      for (int ni = 0; ni < 4; ++ni)
        acc[m][ni] = MFMA(af[m], bf[ni], acc[m][ni]);
    __builtin_amdgcn_s_setprio(0);
  }

  // ---- epilogue ----
  const int rb = (lane >> 4) << 2;
  const int cl = lane & 15;
  if (MODE == 0) {
    const int g = n_base + n0;
    const int which = g / DMODEL;
    const int col0 = g - which * DMODEL;
    ushort* dst = (which == 0) ? (ushort*)out0 : (which == 1) ? out1 : out2;
#pragma unroll
    for (int mi = 0; mi < 8; ++mi)
#pragma unroll
      for (int j = 0; j < 4; ++j) {
        const int l = m0 + wm * 128 + mi * 16 + rb + j;
        const size_t rbase = (size_t)l * DMODEL + col0 + wn * 64 + cl;
        if (which < 2) {
#pragma unroll
          for (int ni = 0; ni < 4; ++ni) dst[rbase + ni * 16] = f2h(acc[mi][ni][j]);
        } else {
#pragma unroll
          for (int ni = 0; ni < 4; ++ni) dst[rbase + ni * 16] = f2bf(acc[mi][ni][j]);
        }
      }
  } else if (MODE == 1) {
    float* outf = (float*)out0;
    const float* bias = (m0 < L_TXT) ? biasLo : biasHi;
    const int rofs = (m0 < L_TXT) ? L_IMG : -L_TXT;  // enc rows after img block
    float bv[4];
#pragma unroll
    for (int ni = 0; ni < 4; ++ni) bv[ni] = bias[n0 + wn * 64 + ni * 16 + cl];
#pragma unroll
    for (int mi = 0; mi < 8; ++mi)
#pragma unroll
      for (int j = 0; j < 4; ++j) {
        const int r = m0 + wm * 128 + mi * 16 + rb + j + rofs;
        const size_t rbase = (size_t)r * N + n0 + wn * 64 + cl;
#pragma unroll
        for (int ni = 0; ni < 4; ++ni) outf[rbase + ni * 16] = acc[mi][ni][j] + bv[ni];
      }
  } else if (MODE == 2) {
    // PV: normalize by fused-softmax row sum (biasLo = RS)
    ushort* outb = (ushort*)out0;
#pragma unroll
    for (int mi = 0; mi < 8; ++mi)
#pragma unroll
      for (int j = 0; j < 4; ++j) {
        const int r = m0 + wm * 128 + mi * 16 + rb + j;
        const float inv = 1.0f / biasLo[r];
        const size_t rbase = (size_t)r * N + n0 + wn * 64 + cl;
#pragma unroll
        for (int ni = 0; ni < 4; ++ni) outb[rbase + ni * 16] = f2h(acc[mi][ni][j] * inv);
      }
  } else if (MODE == 3) {
    // S: write P = exp2((S - 32) * log2e) as bf16 (softmax exp fused; normalize in PV)
    ushort* outb = (ushort*)out0;
#pragma unroll
    for (int mi = 0; mi < 8; ++mi)
#pragma unroll
      for (int j = 0; j < 4; ++j) {
        const int r = m0 + wm * 128 + mi * 16 + rb + j;
        const size_t rbase = (size_t)r * N + n0 + wn * 64 + cl;
#pragma unroll
        for (int ni = 0; ni < 4; ++ni)
          outb[rbase + ni * 16] = f2bf(exp2f((acc[mi][ni][j] - S_SHIFT) * LOG2E));
      }
  } else {
    // V^T direct: plain bf16 out (rows = d, cols = l)
    ushort* outb = (ushort*)out0;
#pragma unroll
    for (int mi = 0; mi < 8; ++mi)
#pragma unroll
      for (int j = 0; j < 4; ++j) {
        const int r = m0 + wm * 128 + mi * 16 + rb + j;
        const size_t rbase = (size_t)r * N + n0 + wn * 64 + cl;
#pragma unroll
        for (int ni = 0; ni < 4; ++ni) outb[rbase + ni * 16] = f2bf(acc[mi][ni][j]);
      }
  }
}

// ---------------- fused RMSNorm + RoPE on merged Q,K [l][3072] fp16; f32 params --------
__global__ void norm_rope(ushort* __restrict__ Q, ushort* __restrict__ Kg,
                          const float* __restrict__ rope,
                          const float* __restrict__ qn, const float* __restrict__ kn,
                          const float* __restrict__ eqn, const float* __restrict__ ekn) {
  const int idx = (blockIdx.x << 2) + (threadIdx.x >> 6);  // (l*24 + h)
  const int lane = threadIdx.x & 63;
  const int h = idx % NH, l = idx / NH;
  const float* qsc = (l < L_TXT) ? eqn : qn;
  const float* ksc = (l < L_TXT) ? ekn : kn;
  const size_t base = (size_t)l * DMODEL + h * HD + (lane << 1);
  const f32x4 fcv = *(const f32x4*)(rope + ((size_t)l * 64 + lane) * 4);
  const float fa = fcv[0], fb = fcv[1], fc = fcv[2], fd = fcv[3];
  const float s0 = qsc[lane << 1], s1 = qsc[(lane << 1) + 1];
  const float t0 = ksc[lane << 1], t1 = ksc[(lane << 1) + 1];
  {
    const uint32_t qv = *(const uint32_t*)&Q[base];
    float x0 = h2f((ushort)(qv & 0xffff)), x1 = h2f((ushort)(qv >> 16));
    float ss = x0 * x0 + x1 * x1;
#pragma unroll
    for (int m = 1; m < 64; m <<= 1) ss += __shfl_xor(ss, m);
    const float r = rsqrtf(ss * (1.0f / 128.0f) + 1e-6f);
    x0 *= r * s0;
    x1 *= r * s1;
    const float o0 = (fa * x0 + fb * x1) * 0.08838834764831845f;
    const float o1 = (fc * x0 + fd * x1) * 0.08838834764831845f;
    *(uint32_t*)&Q[base] = (uint32_t)f2h(o0) | ((uint32_t)f2h(o1) << 16);
  }
  {
    const uint32_t kv = *(const uint32_t*)&Kg[base];
    float x0 = h2f((ushort)(kv & 0xffff)), x1 = h2f((ushort)(kv >> 16));
    float ss = x0 * x0 + x1 * x1;
#pragma unroll
    for (int m = 1; m < 64; m <<= 1) ss += __shfl_xor(ss, m);
    const float r = rsqrtf(ss * (1.0f / 128.0f) + 1e-6f);
    x0 *= r * t0;
    x1 *= r * t1;
    const float o0 = fa * x0 + fb * x1;
    const float o1 = fc * x0 + fd * x1;
    *(uint32_t*)&Kg[base] = (uint32_t)f2h(o0) | ((uint32_t)f2h(o1) << 16);
  }
}

extern "C" void kernel_launch(void* const* d_in, const int* in_sizes, int n_in,
                              void* d_out, int out_size, void* d_ws, size_t ws_size,
                              hipStream_t stream) {
  (void)in_sizes; (void)n_in; (void)out_size;
  const float* hidden  = (const float*)d_in[0];
  const float* enc     = (const float*)d_in[1];
  const float* rope    = (const float*)d_in[2];
  const float* W_iqkv  = (const float*)d_in[3];
  const float* W_eqkv  = (const float*)d_in[4];
  const float* W_iproj = (const float*)d_in[5];
  const float* b_iproj = (const float*)d_in[6];
  const float* W_eproj = (const float*)d_in[7];
  const float* b_eproj = (const float*)d_in[8];
  const float* qn  = (const float*)d_in[9];
  const float* kn  = (const float*)d_in[10];
  const float* eqn = (const float*)d_in[11];
  const float* ekn = (const float*)d_in[12];
  float* out = (float*)d_out;

  // ws layout (ushort units). Base footprint 127.4 MB:
  //   R0 = S region (42.5 MB): CF during QKV -> P (bf16) -> proj W^T pair
  //   QR (->AO), KR, VR (V^T bf16 [3072][4608] — written directly on big path)
  // Big-ws path (>= 241 MB): two full QKV W^T beyond the base footprint; V^T is a
  // direct GEMM (A = Wv^T rows of W^T, B = CF as [N][K]) — no transpose kernel.
  // RS (rowsums, 18 KB f32) lives in d_out (free until proj writes it).
  const size_t SZ_S  = (size_t)L_TOT * L_TOT;
  const size_t SZ_LD = (size_t)L_TOT * DMODEL;
  const size_t SZ_WH = (size_t)L_TOT * DMODEL;       // half-W^T = [4608][3072]
  const size_t SZ_W  = (size_t)NQKV * DMODEL;        // full W^T = [9216][3072]
  ushort* R0  = (ushort*)d_ws;
  ushort* CF  = R0;                       // [enc; hidden] fp16 [4608][3072]
  ushort* S   = R0;                       // P (bf16) after S-GEMM
  ushort* QR  = R0 + SZ_S;
  ushort* KR  = QR + SZ_LD;
  ushort* VR  = KR + SZ_LD;               // big: V^T ; fallback: V row-major
  ushort* VT  = KR;            // fallback alias: V^T after S GEMM (KR dead)
  ushort* AO  = QR;            // alias: QR dead after S GEMM
  ushort* WTe = (ushort*)out;  // enc half-W^T in d_out (fallback path)
  ushort* WTi = WTe + SZ_WH;   // img half-W^T in d_out (fallback path)
  ushort* WQe = VR + SZ_LD;    // full enc W^T (big-ws path)
  ushort* WQi = WQe + SZ_W;    // full img W^T (big-ws path)
  ushort* WPi = R0;                              // img proj W^T [3072][3072]
  ushort* WPe = R0 + (size_t)DMODEL * DMODEL;    // enc proj W^T
  float*  RS  = (float*)d_out;                   // row sums (consumed before proj)
  const bool big = ws_size >= (SZ_S + 3 * SZ_LD + 2 * SZ_W) * sizeof(ushort);

  dim3 blk(256);
  // inputs -> fp16, concatenated [enc; hidden]
  cvt_f32_f16<<<dim3(L_TXT * DMODEL / 8 / 256), blk, 0, stream>>>(enc, CF,
                                                                  L_TXT * DMODEL / 8);
  cvt_f32_f16<<<dim3(L_IMG * DMODEL / 8 / 256), blk, 0, stream>>>(
      hidden, CF + (size_t)L_TXT * DMODEL, L_IMG * DMODEL / 8);
  if (big) {
    // QK: merged dispatch over N=6144 (Q,K columns of W^T)
    tconv_w<<<dim3(NQKV / 64, DMODEL / 64), blk, 0, stream>>>(W_eqkv, NQKV, 0, WQe);
    tconv_w<<<dim3(NQKV / 64, DMODEL / 64), blk, 0, stream>>>(W_iqkv, NQKV, 0, WQi);
    gemm256<0><<<dim3(L_TOT / 256, 2 * DMODEL / 256), dim3(512), 0, stream>>>(
        CF, nullptr, DMODEL, WQe, WQi, DMODEL, 2 * DMODEL, DMODEL,
        QR, KR, nullptr, nullptr, nullptr, 0);
    // V^T direct: M = 3072 (d), N = 4608 (l); A = Wv^T slice, select by n0 (enc/img)
    gemm256<4><<<dim3(DMODEL / 256, L_TOT / 256), dim3(512), 0, stream>>>(
        WQe + (size_t)2 * DMODEL * DMODEL, WQi + (size_t)2 * DMODEL * DMODEL, DMODEL,
        CF, CF, DMODEL, L_TOT, DMODEL, VR, nullptr, nullptr, nullptr, nullptr, 0);
  } else {
    // fallback: two 4608-col halves through d_out scratch; V row-major + tconv_h
    for (int h = 0; h < 2; ++h) {
      const int c0 = h * 4608;
      tconv_w<<<dim3(72, 48), blk, 0, stream>>>(W_eqkv, NQKV, c0, WTe);
      tconv_w<<<dim3(72, 48), blk, 0, stream>>>(W_iqkv, NQKV, c0, WTi);
      gemm256<0><<<dim3(L_TOT / 256, 18), dim3(512), 0, stream>>>(
          CF, nullptr, DMODEL, WTe, WTi, DMODEL, 4608, DMODEL,
          QR, KR, VR, nullptr, nullptr, c0);
    }
  }
  // per-head RMSNorm + RoPE (attn scale folded into Q)
  norm_rope<<<dim3(L_TOT * NH / 4), blk, 0, stream>>>(QR, KR, rope, qn, kn, eqn, ekn);
  // P = exp2((Q K^T - 32)*log2e) as bf16 (softmax exp fused into epilogue)
  gemm256<3><<<dim3(L_TOT / 256, L_TOT / 256), dim3(512), 0, stream>>>(
      QR, nullptr, DMODEL, KR, KR, DMODEL, L_TOT, DMODEL, S, nullptr, nullptr,
      nullptr, nullptr, 0);
  // row sums of P (f32)
  rowsum<<<dim3(L_TOT), blk, 0, stream>>>(S, RS);
  ushort* vtp = VR;
  if (!big) {
    // fallback: V^T via conflict-free tiled transpose (KR region now free)
    tconv_h<<<dim3(48, 72), blk, 0, stream>>>(VR, VT, L_TOT, DMODEL);
    vtp = VT;
  }
  // AO = (P @ V) / RS[row]  (bf16 MFMA; normalization fused into epilogue)
  gemm256<2><<<dim3(L_TOT / 256, DMODEL / 256), dim3(512), 0, stream>>>(
      S, nullptr, L_TOT, vtp, vtp, L_TOT, DMODEL, L_TOT, AO, nullptr, nullptr,
      RS, nullptr, 0);
  // output projections: merged enc+img, per-block weight/bias select + row remap
  tconv_w<<<dim3(48, 48), blk, 0, stream>>>(W_iproj, DMODEL, 0, WPi);
  tconv_w<<<dim3(48, 48), blk, 0, stream>>>(W_eproj, DMODEL, 0, WPe);
  gemm256<1><<<dim3(L_TOT / 256, DMODEL / 256), dim3(512), 0, stream>>>(
      AO, nullptr, DMODEL, WPe, WPi, DMODEL, DMODEL, DMODEL,
      out, nullptr, nullptr, b_eproj, b_iproj, 0);
}